// Round 5
// baseline (437.396 us; speedup 1.0000x reference)
//
#include <hip/hip_runtime.h>
#include <type_traits>
#include <utility>

#define DI __device__ __forceinline__

typedef unsigned short u16;
typedef float f32x4 __attribute__((ext_vector_type(4)));
typedef float f32x16 __attribute__((ext_vector_type(16)));
typedef short s16x8 __attribute__((ext_vector_type(8)));
typedef __bf16 bf16x8 __attribute__((ext_vector_type(8)));

// ---- pick whichever vector type the gfx950 bf16 MFMA builtin accepts ----
template <typename V, typename = void>
struct mfma_ok : std::false_type {};
template <typename V>
struct mfma_ok<V, std::void_t<decltype(__builtin_amdgcn_mfma_f32_16x16x32_bf16(
    std::declval<V>(), std::declval<V>(), std::declval<f32x4>(), 0, 0, 0))>>
    : std::true_type {};
using frag_t = std::conditional_t<mfma_ok<bf16x8>::value, bf16x8, s16x8>;

union U128 {
  int4 i;
  frag_t f;
  u16 s[8];
};

DI f32x4 mfma16(const U128& a, const U128& b, f32x4 c) {
  return __builtin_amdgcn_mfma_f32_16x16x32_bf16(a.f, b.f, c, 0, 0, 0);
}
DI f32x16 mfma32(const U128& a, const U128& b, f32x16 c) {
  return __builtin_amdgcn_mfma_f32_32x32x16_bf16(a.f, b.f, c, 0, 0, 0);
}

DI u16 f2b(float x) {  // fp32 -> bf16 RNE (finite inputs)
  union { float f; unsigned u; } v; v.f = x;
  unsigned r = v.u + 0x7FFFu + ((v.u >> 16) & 1u);
  return (u16)(r >> 16);
}

#if __has_builtin(__builtin_amdgcn_exp2f)
#define EXP2F __builtin_amdgcn_exp2f
#else
#define EXP2F exp2f
#endif

typedef __attribute__((address_space(1))) void gas_t;
typedef __attribute__((address_space(3))) void las_t;
DI void gll16(const void* g, void* l) {  // async global->LDS, 16B/lane
  __builtin_amdgcn_global_load_lds((gas_t*)g, (las_t*)l, 16, 0, 0);
}

// ---------------- elementwise fp32 -> bf16 ----------------
__global__ __launch_bounds__(256) void k_conv_bf16(const float* __restrict__ in,
                                                   u16* __restrict__ out, int n4) {
  int i = blockIdx.x * 256 + threadIdx.x;
  if (i >= n4) return;
  float4 v = ((const float4*)in)[i];
  ushort4 o;
  o.x = f2b(v.x); o.y = f2b(v.y); o.z = f2b(v.z); o.w = f2b(v.w);
  ((ushort4*)out)[i] = o;
}

// ---------------- fp32 [R][C] -> bf16 [C][R] (weights to B^T form) ----------------
__global__ __launch_bounds__(256) void k_transpose_f2b(const float* __restrict__ in,
                                                       u16* __restrict__ out,
                                                       int R, int C) {
  __shared__ __attribute__((aligned(16))) u16 Tb[64][68];
  int t = threadIdx.x;
  long r0 = (long)blockIdx.y * 64, c0 = (long)blockIdx.x * 64;
  int cq = (t & 15) * 4, rr = t >> 4;
#pragma unroll
  for (int it = 0; it < 4; ++it) {
    int r = rr + it * 16;
    float4 v = *(const float4*)(in + (r0 + r) * C + c0 + cq);
    Tb[r][cq + 0] = f2b(v.x); Tb[r][cq + 1] = f2b(v.y);
    Tb[r][cq + 2] = f2b(v.z); Tb[r][cq + 3] = f2b(v.w);
  }
  __syncthreads();
#pragma unroll
  for (int it = 0; it < 2; ++it) {
    int ci = it * 256 + t;
    int cc = ci >> 3, ch = ci & 7, rb = ch * 8;
    unsigned p0 = Tb[rb + 0][cc] | ((unsigned)Tb[rb + 1][cc] << 16);
    unsigned p1 = Tb[rb + 2][cc] | ((unsigned)Tb[rb + 3][cc] << 16);
    unsigned p2 = Tb[rb + 4][cc] | ((unsigned)Tb[rb + 5][cc] << 16);
    unsigned p3 = Tb[rb + 6][cc] | ((unsigned)Tb[rb + 7][cc] << 16);
    *(int4*)(out + (c0 + cc) * R + r0 + rb) = make_int4(p0, p1, p2, p3);
  }
}

// ---------------- C[M][N] = A[M][K] * Bt[N][K]^T + bias, bf16 in, bf16/f32 out ----
// BK=64, XOR chunk swizzle: LDS row = 128 B (== 0 mod 32 banks); global chunk
// (cp ^ row&7) lands in LDS slot cp, reader XORs back -> <=2-way conflicts (free).
template <bool BF16OUT>
__global__ __launch_bounds__(256, 4) void k_gemm_bt(const u16* __restrict__ A,
                                                    const u16* __restrict__ Bt,
                                                    const float* __restrict__ bias,
                                                    void* __restrict__ Cout,
                                                    int M, int N, int K) {
  __shared__ __attribute__((aligned(16))) u16 As[128 * 64];
  __shared__ __attribute__((aligned(16))) u16 Bs[128 * 64];
  int t = threadIdx.x;
  int lane = t & 63, w = t >> 6, quad = lane >> 4, l15 = lane & 15;
  long m0 = (long)blockIdx.y * 128, n0 = (long)blockIdx.x * 128;
  int wr = (w >> 1) * 64, wc = (w & 1) * 64;
  int sw = l15 & 7;  // row&7 for all frag rows this lane touches
  f32x4 acc[4][4] = {};
  for (int k0 = 0; k0 < K; k0 += 64) {
    __syncthreads();
#pragma unroll
    for (int it = 0; it < 4; ++it) {
      int ci = it * 256 + t;
      int row = ci >> 3, cl = (ci & 7) ^ (row & 7);
      gll16(A + (m0 + row) * K + k0 + cl * 8, As + ci * 8);
      gll16(Bt + (n0 + row) * K + k0 + cl * 8, Bs + ci * 8);
    }
    __syncthreads();
#pragma unroll
    for (int kk = 0; kk < 2; ++kk) {
      U128 a[4], b[4];
#pragma unroll
      for (int i = 0; i < 4; ++i)
        a[i].i = *(const int4*)(As + (wr + i * 16 + l15) * 64 + (((kk * 4 + quad) ^ sw) << 3));
#pragma unroll
      for (int j = 0; j < 4; ++j)
        b[j].i = *(const int4*)(Bs + (wc + j * 16 + l15) * 64 + (((kk * 4 + quad) ^ sw) << 3));
#pragma unroll
      for (int i = 0; i < 4; ++i)
#pragma unroll
        for (int j = 0; j < 4; ++j)
          acc[i][j] = mfma16(a[i], b[j], acc[i][j]);
    }
  }
  float bj[4];
#pragma unroll
  for (int j = 0; j < 4; ++j) bj[j] = bias[n0 + wc + j * 16 + l15];
#pragma unroll
  for (int i = 0; i < 4; ++i) {
#pragma unroll
    for (int r = 0; r < 4; ++r) {
      long row = m0 + wr + i * 16 + quad * 4 + r;
#pragma unroll
      for (int j = 0; j < 4; ++j) {
        long col = n0 + wc + j * 16 + l15;
        float v = acc[i][j][r] + bj[j];
        if (BF16OUT) {
          unsigned pb = f2b(v);
          unsigned other = __shfl_xor(pb, 1);
          if (!(l15 & 1))  // even-col lane stores packed bf16 pair
            ((unsigned*)Cout)[(row * N + col) >> 1] = pb | (other << 16);
        } else {
          unsigned bits = __float_as_uint(v);
          unsigned other = __shfl_xor(bits, 1);
          if (!(l15 & 1)) {  // even-col lane stores packed fp32 pair (dwordx2)
            uint2 pr; pr.x = bits; pr.y = other;
            *(uint2*)((float*)Cout + row * N + col) = pr;
          }
        }
      }
    }
  }
}

// ---- extract per-head K (contiguous) and V^T:
//   kb[bh*2048 + s][d]   = qkv[b*S+s][h*384+128+d]   (int4 copy, coalesced)
//   vt[bh*128 + d][s]    = qkv[b*S+s][h*384+256+d]   (transpose via LDS)
__global__ __launch_bounds__(256) void k_extract_kvt(const u16* __restrict__ qkv,
                                                     u16* __restrict__ kb,
                                                     u16* __restrict__ vt) {
  __shared__ __attribute__((aligned(16))) u16 Vb[64][136];
  int t = threadIdx.x;
  int s0 = blockIdx.x * 64;
  int bh = blockIdx.y, b = bh >> 4, h = bh & 15;
  long rowbase = (long)b * 2048 + s0;
  long krowout = (long)bh * 2048 + s0;
#pragma unroll
  for (int it = 0; it < 4; ++it) {  // K: 64 s x 16 chunks
    int ci = it * 256 + t;
    int s = ci >> 4, ch = ci & 15;
    int4 v = *(const int4*)(qkv + (rowbase + s) * 6144 + h * 384 + 128 + ch * 8);
    *(int4*)(kb + (krowout + s) * 128 + ch * 8) = v;
  }
#pragma unroll
  for (int it = 0; it < 4; ++it) {  // V: stage to LDS
    int ci = it * 256 + t;
    int s = ci >> 4, ch = ci & 15;
    int4 v = *(const int4*)(qkv + (rowbase + s) * 6144 + h * 384 + 256 + ch * 8);
    *(int4*)(&Vb[s][ch * 8]) = v;
  }
  __syncthreads();
  long outbase = (long)bh * 128 * 2048 + s0;
#pragma unroll
  for (int it = 0; it < 4; ++it) {
    int ci = it * 256 + t;
    int d = ci >> 3, ch = ci & 7, sb = ch * 8;
    unsigned p0 = Vb[sb + 0][d] | ((unsigned)Vb[sb + 1][d] << 16);
    unsigned p1 = Vb[sb + 2][d] | ((unsigned)Vb[sb + 3][d] << 16);
    unsigned p2 = Vb[sb + 4][d] | ((unsigned)Vb[sb + 5][d] << 16);
    unsigned p3 = Vb[sb + 6][d] | ((unsigned)Vb[sb + 7][d] << 16);
    *(int4*)(vt + outbase + (long)d * 2048 + sb) = make_int4(p0, p1, p2, p3);
  }
}

// ---------------- flash attention v3: key-split for occupancy ----------------
// Block: 256 thr / 4 waves, 64 q-rows. wave w: qg = w&1 (32 q), kg = w>>1
// (key half [kg*1024, kg*1024+1024)). Grid 32x32 = 1024 blocks -> 3 blocks/CU
// (launch_bounds(256,3)), 12 waves/CU vs v2's 8. Per-half LDS: K 32-key tiles
// (8KB, 16-chunk ^&15 swizzle), V 64-key tiles staged on even iters (16KB,
// 8-chunk ^&7). Total 48KB. S^T = K*Q^T; P^T in-register (exp2, no max);
// O^T = V^T*P^T. Key-halves merged at end via LDS fp32 partials (stride 129).
__global__ __launch_bounds__(256, 3) void k_flash(const u16* __restrict__ qkv,
                                                  const u16* __restrict__ kb,
                                                  const u16* __restrict__ vt,
                                                  u16* __restrict__ attn) {
  __shared__ __attribute__((aligned(16))) char smraw[49152];
  u16* Ks = (u16*)smraw;              // [2][32*128]  16 KB
  u16* Vts = (u16*)(smraw + 16384);   // [2][128*64]  32 KB
  float* Om = (float*)smraw;          // merge overlay: [2][32][129] fp32
  float* Lm = (float*)(smraw + 33024);

  int t = threadIdx.x;
  int lane = t & 63, w = t >> 6, l31 = lane & 31, h = lane >> 5;
  int qg = w & 1, kg = w >> 1, tl = t & 127;
  int q0 = blockIdx.x * 64 + qg * 32;
  int bh = blockIdx.y, b = bh >> 4, hd = bh & 15;

  // Q B-frags: B[k=dh][n=q]: lane holds Q[q0+l31][dht*16 + h*8 + j]
  const u16* qbase = qkv + ((long)b * 2048 + q0 + l31) * 6144 + hd * 384;
  U128 qf[8];
#pragma unroll
  for (int dht = 0; dht < 8; ++dht)
    qf[dht].i = *(const int4*)(qbase + dht * 16 + h * 8);

  f32x16 O[4] = {};  // O^T: col=q, rows=dh (4 blocks of 32)
  float lsum = 0.f;
  const float CEXP = 0.08838834764831845f * 1.4426950408889634f;  // cs*log2(e)
  const u16* kbh = kb + (long)bh * 2048 * 128;
  long vbase = (long)bh * 128 * 2048;
  u16* KsH = Ks + kg * 4096;
  u16* VtsH = Vts + kg * 8192;
  int kstart = kg * 1024;
  int sw15 = l31 & 15;

  for (int tile = 0; tile < 32; ++tile) {
    int k0 = kstart + tile * 32;
    __syncthreads();
#pragma unroll
    for (int it = 0; it < 4; ++it) {  // K tile: 32 keys x 128 dh, per-half staging
      int ci = it * 128 + tl;
      int key = ci >> 4, cp = ci & 15, cl = cp ^ (key & 15);
      gll16(kbh + (long)(k0 + key) * 128 + cl * 8, KsH + ci * 8);
    }
    if (!(tile & 1)) {  // V tile: 128 dh x 64 keys, covers this tile + next
#pragma unroll
      for (int it = 0; it < 8; ++it) {
        int ci = it * 128 + tl;
        int d = ci >> 3, cp = ci & 7, cl = cp ^ (d & 7);
        gll16(vt + vbase + (long)d * 2048 + k0 + cl * 8, VtsH + ci * 8);
      }
    }
    __syncthreads();

    // S^T = K * Q^T  (32 keys x 32 q)
    f32x16 St = {};
#pragma unroll
    for (int dht = 0; dht < 8; ++dht) {
      U128 kf;
      kf.i = *(const int4*)(KsH + l31 * 128 + (((dht * 2 + h) ^ sw15) << 3));
      St = mfma32(kf, qf[dht], St);
    }

    // P = exp(S*cs), no max subtraction; accumulate row-sum (all regs share q)
    float pk[16];
#pragma unroll
    for (int r = 0; r < 16; ++r) {
      float p = EXP2F(St[r] * CEXP);
      pk[r] = p;
      lsum += p;
    }

    // Build P^T B-frags via lane-half exchange
    U128 pf[2];
#pragma unroll
    for (int g = 0; g < 2; ++g) {
      float tmp[4], recv[4], lo[4], hi[4];
#pragma unroll
      for (int i = 0; i < 4; ++i)
        tmp[i] = h ? pk[g * 8 + i] : pk[g * 8 + 4 + i];
#pragma unroll
      for (int i = 0; i < 4; ++i) recv[i] = __shfl_xor(tmp[i], 32);
#pragma unroll
      for (int i = 0; i < 4; ++i) {
        lo[i] = h ? recv[i] : pk[g * 8 + i];
        hi[i] = h ? pk[g * 8 + 4 + i] : recv[i];
      }
      unsigned w0 = f2b(lo[0]) | ((unsigned)f2b(lo[1]) << 16);
      unsigned w1 = f2b(lo[2]) | ((unsigned)f2b(lo[3]) << 16);
      unsigned w2 = f2b(hi[0]) | ((unsigned)f2b(hi[1]) << 16);
      unsigned w3 = f2b(hi[2]) | ((unsigned)f2b(hi[3]) << 16);
      pf[g].i = make_int4(w0, w1, w2, w3);
    }

    // O^T += V^T * P^T  (V chunk offset by tile parity within 64-key V tile)
    int koff = (tile & 1) * 4;
#pragma unroll
    for (int kt = 0; kt < 2; ++kt)
#pragma unroll
      for (int dht = 0; dht < 4; ++dht) {
        int vrow = dht * 32 + l31;
        U128 vf;
        vf.i = *(const int4*)(VtsH + vrow * 64 + (((koff + kt * 2 + h) ^ (vrow & 7)) << 3));
        O[dht] = mfma32(vf, pf[kt], O[dht]);
      }
  }

  // ---- merge key halves via LDS ----
  float lhalf = lsum + __shfl_xor(lsum, 32);  // per-q sum over this wave's keys
  __syncthreads();
  if (kg == 1) {
    if (lane < 32) Lm[qg * 32 + l31] = lhalf;
#pragma unroll
    for (int dht = 0; dht < 4; ++dht)
#pragma unroll
      for (int r = 0; r < 16; ++r) {
        int dh = dht * 32 + (r & 3) + 8 * (r >> 2) + 4 * h;
        Om[(qg * 32 + l31) * 129 + dh] = O[dht][r];
      }
  }
  __syncthreads();
  if (kg == 0) {
    float ltot = lhalf + Lm[qg * 32 + l31];
    float inv = 1.f / ltot;
    long orow = (long)b * 2048 + q0 + l31;
    u16* ob = attn + orow * 2048 + hd * 128;
    const float* Oq = Om + (qg * 32 + l31) * 129;
#pragma unroll
    for (int dht = 0; dht < 4; ++dht)
#pragma unroll
      for (int g = 0; g < 4; ++g) {
        int dh = dht * 32 + g * 8 + h * 4;
        float v0 = (O[dht][4 * g + 0] + Oq[dh + 0]) * inv;
        float v1 = (O[dht][4 * g + 1] + Oq[dh + 1]) * inv;
        float v2 = (O[dht][4 * g + 2] + Oq[dh + 2]) * inv;
        float v3 = (O[dht][4 * g + 3] + Oq[dh + 3]) * inv;
        uint2 pkd;
        pkd.x = f2b(v0) | ((unsigned)f2b(v1) << 16);
        pkd.y = f2b(v2) | ((unsigned)f2b(v3) << 16);
        *(uint2*)(ob + dh) = pkd;
      }
  }
}

extern "C" void kernel_launch(void* const* d_in, const int* in_sizes, int n_in,
                              void* d_out, int out_size, void* d_ws, size_t ws_size,
                              hipStream_t stream) {
  const float* x    = (const float*)d_in[0];
  const float* Wqkv = (const float*)d_in[1];
  const float* bqkv = (const float*)d_in[2];
  const float* Wout = (const float*)d_in[3];
  const float* bout = (const float*)d_in[4];
  float* out = (float*)d_out;
  char* ws = (char*)d_ws;

  // Workspace overlay (peak 75,497,472 B in ws; d_out = 33.55 MB doubles as scratch):
  //   phase A: xb (bf16 x, 16.78 MB)  -> d_out[0, 16.78M)  [dead after GEMM1]
  //            wqkvt (25.17 MB)       -> ws[0, 25165824)   [dead after GEMM1]
  //            qkvb (50.33 MB)        -> ws[25165824, 75497472)
  //   phase B: vt (16.78 MB)          -> d_out[0, 16.78M)      [xb dead]
  //            kb (16.78 MB)          -> d_out[16.78M, 33.55M)
  //            woutt (8.39 MB)        -> ws[0, 8388608)
  //            attnb (16.78 MB)       -> ws[8388608, 25165824)
  //   vt/kb dead before GEMM2 writes d_out.
  if (ws_size < 75497472u) return;  // diagnostic guard: fail cleanly, not fault

  u16* xb    = (u16*)d_out;
  u16* wqkvt = (u16*)(ws);
  u16* qkvb  = (u16*)(ws + 25165824);
  u16* vtb   = (u16*)d_out;                      // after GEMM1 (xb dead)
  u16* kbuf  = (u16*)((char*)d_out + 16777216);  // after GEMM1
  u16* woutt = (u16*)(ws);                       // after GEMM1
  u16* attnb = (u16*)(ws + 8388608);             // after GEMM1

  // x: 2*2048*2048 = 8,388,608 floats = 2,097,152 float4s
  k_conv_bf16<<<8192, 256, 0, stream>>>(x, xb, 2097152);
  k_transpose_f2b<<<dim3(96, 32), 256, 0, stream>>>(Wqkv, wqkvt, 2048, 6144);
  k_gemm_bt<true><<<dim3(48, 32), 256, 0, stream>>>(xb, wqkvt, bqkv, qkvb, 4096, 6144, 2048);
  k_extract_kvt<<<dim3(32, 32), 256, 0, stream>>>(qkvb, kbuf, vtb);
  k_transpose_f2b<<<dim3(32, 32), 256, 0, stream>>>(Wout, woutt, 2048, 2048);
  k_flash<<<dim3(32, 32), 256, 0, stream>>>(qkvb, kbuf, vtb, attnb);
  k_gemm_bt<false><<<dim3(16, 32), 256, 0, stream>>>(attnb, woutt, bout, out, 4096, 2048, 2048);
}

// Round 6
// 397.377 us; speedup vs baseline: 1.1007x; 1.1007x over previous
//
#include <hip/hip_runtime.h>
#include <type_traits>
#include <utility>

#define DI __device__ __forceinline__

typedef unsigned short u16;
typedef float f32x4 __attribute__((ext_vector_type(4)));
typedef float f32x16 __attribute__((ext_vector_type(16)));
typedef short s16x8 __attribute__((ext_vector_type(8)));
typedef __bf16 bf16x8 __attribute__((ext_vector_type(8)));

// ---- pick whichever vector type the gfx950 bf16 MFMA builtin accepts ----
template <typename V, typename = void>
struct mfma_ok : std::false_type {};
template <typename V>
struct mfma_ok<V, std::void_t<decltype(__builtin_amdgcn_mfma_f32_16x16x32_bf16(
    std::declval<V>(), std::declval<V>(), std::declval<f32x4>(), 0, 0, 0))>>
    : std::true_type {};
using frag_t = std::conditional_t<mfma_ok<bf16x8>::value, bf16x8, s16x8>;

union U128 {
  int4 i;
  frag_t f;
  u16 s[8];
};

DI f32x4 mfma16(const U128& a, const U128& b, f32x4 c) {
  return __builtin_amdgcn_mfma_f32_16x16x32_bf16(a.f, b.f, c, 0, 0, 0);
}
DI f32x16 mfma32(const U128& a, const U128& b, f32x16 c) {
  return __builtin_amdgcn_mfma_f32_32x32x16_bf16(a.f, b.f, c, 0, 0, 0);
}

DI u16 f2b(float x) {  // fp32 -> bf16 RNE (finite inputs)
  union { float f; unsigned u; } v; v.f = x;
  unsigned r = v.u + 0x7FFFu + ((v.u >> 16) & 1u);
  return (u16)(r >> 16);
}

#if __has_builtin(__builtin_amdgcn_exp2f)
#define EXP2F __builtin_amdgcn_exp2f
#else
#define EXP2F exp2f
#endif

typedef __attribute__((address_space(1))) void gas_t;
typedef __attribute__((address_space(3))) void las_t;
DI void gll16(const void* g, void* l) {  // async global->LDS, 16B/lane
  __builtin_amdgcn_global_load_lds((gas_t*)g, (las_t*)l, 16, 0, 0);
}

// ---------------- elementwise fp32 -> bf16 ----------------
__global__ __launch_bounds__(256) void k_conv_bf16(const float* __restrict__ in,
                                                   u16* __restrict__ out, int n4) {
  int i = blockIdx.x * 256 + threadIdx.x;
  if (i >= n4) return;
  float4 v = ((const float4*)in)[i];
  ushort4 o;
  o.x = f2b(v.x); o.y = f2b(v.y); o.z = f2b(v.z); o.w = f2b(v.w);
  ((ushort4*)out)[i] = o;
}

// ---------------- fp32 [R][C] -> bf16 [C][R] (weights to B^T form) ----------------
__global__ __launch_bounds__(256) void k_transpose_f2b(const float* __restrict__ in,
                                                       u16* __restrict__ out,
                                                       int R, int C) {
  __shared__ __attribute__((aligned(16))) u16 Tb[64][68];
  int t = threadIdx.x;
  long r0 = (long)blockIdx.y * 64, c0 = (long)blockIdx.x * 64;
  int cq = (t & 15) * 4, rr = t >> 4;
#pragma unroll
  for (int it = 0; it < 4; ++it) {
    int r = rr + it * 16;
    float4 v = *(const float4*)(in + (r0 + r) * C + c0 + cq);
    Tb[r][cq + 0] = f2b(v.x); Tb[r][cq + 1] = f2b(v.y);
    Tb[r][cq + 2] = f2b(v.z); Tb[r][cq + 3] = f2b(v.w);
  }
  __syncthreads();
#pragma unroll
  for (int it = 0; it < 2; ++it) {
    int ci = it * 256 + t;
    int cc = ci >> 3, ch = ci & 7, rb = ch * 8;
    unsigned p0 = Tb[rb + 0][cc] | ((unsigned)Tb[rb + 1][cc] << 16);
    unsigned p1 = Tb[rb + 2][cc] | ((unsigned)Tb[rb + 3][cc] << 16);
    unsigned p2 = Tb[rb + 4][cc] | ((unsigned)Tb[rb + 5][cc] << 16);
    unsigned p3 = Tb[rb + 6][cc] | ((unsigned)Tb[rb + 7][cc] << 16);
    *(int4*)(out + (c0 + cc) * R + r0 + rb) = make_int4(p0, p1, p2, p3);
  }
}

// ---------------- C[M][N] = A[M][K] * Bt[N][K]^T + bias ----------------
// BK=64, XOR chunk swizzle (conflict-free, verified R4: SQ_LDS_BANK_CONFLICT=0).
// MODE 0: fp32 packed-pair out to Cout (GEMM2).
// MODE 1: bf16 routed out (GEMM1): N-tile (n0/128)%3 selects Q/K/V of head
//         n0/384; writes contiguous per-head [bh][s][dh] buffers qb/kb/vb.
template <int MODE>
__global__ __launch_bounds__(256, 4) void k_gemm_bt(const u16* __restrict__ A,
                                                    const u16* __restrict__ Bt,
                                                    const float* __restrict__ bias,
                                                    void* __restrict__ Cout,
                                                    u16* __restrict__ qb,
                                                    u16* __restrict__ kbv,
                                                    u16* __restrict__ vb,
                                                    int M, int N, int K) {
  __shared__ __attribute__((aligned(16))) u16 As[128 * 64];
  __shared__ __attribute__((aligned(16))) u16 Bs[128 * 64];
  int t = threadIdx.x;
  int lane = t & 63, w = t >> 6, quad = lane >> 4, l15 = lane & 15;
  long m0 = (long)blockIdx.y * 128, n0 = (long)blockIdx.x * 128;
  int wr = (w >> 1) * 64, wc = (w & 1) * 64;
  int sw = l15 & 7;
  f32x4 acc[4][4] = {};
  for (int k0 = 0; k0 < K; k0 += 64) {
    __syncthreads();
#pragma unroll
    for (int it = 0; it < 4; ++it) {
      int ci = it * 256 + t;
      int row = ci >> 3, cl = (ci & 7) ^ (row & 7);
      gll16(A + (m0 + row) * K + k0 + cl * 8, As + ci * 8);
      gll16(Bt + (n0 + row) * K + k0 + cl * 8, Bs + ci * 8);
    }
    __syncthreads();
#pragma unroll
    for (int kk = 0; kk < 2; ++kk) {
      U128 a[4], b[4];
#pragma unroll
      for (int i = 0; i < 4; ++i)
        a[i].i = *(const int4*)(As + (wr + i * 16 + l15) * 64 + (((kk * 4 + quad) ^ sw) << 3));
#pragma unroll
      for (int j = 0; j < 4; ++j)
        b[j].i = *(const int4*)(Bs + (wc + j * 16 + l15) * 64 + (((kk * 4 + quad) ^ sw) << 3));
#pragma unroll
      for (int i = 0; i < 4; ++i)
#pragma unroll
        for (int j = 0; j < 4; ++j)
          acc[i][j] = mfma16(a[i], b[j], acc[i][j]);
    }
  }
  float bj[4];
#pragma unroll
  for (int j = 0; j < 4; ++j) bj[j] = bias[n0 + wc + j * 16 + l15];

  // routing (wave-uniform): which of q/k/v this N-tile belongs to
  int hidx = (int)(n0 / 384);
  int rsel = (int)(n0 - hidx * 384) >> 7;  // 0=Q 1=K 2=V
  u16* route = (MODE == 1) ? (rsel == 0 ? qb : rsel == 1 ? kbv : vb) : nullptr;

#pragma unroll
  for (int i = 0; i < 4; ++i) {
#pragma unroll
    for (int rr2 = 0; rr2 < 4; ++rr2) {
      long row = m0 + wr + i * 16 + quad * 4 + rr2;
#pragma unroll
      for (int j = 0; j < 4; ++j) {
        float v = acc[i][j][rr2] + bj[j];
        if (MODE == 1) {
          int bidx = (int)(row >> 11), s = (int)(row & 2047);
          long obase = ((long)(bidx * 16 + hidx) * 2048 + s) * 128;
          int dh = wc + j * 16 + l15;
          unsigned pb = f2b(v);
          unsigned other = __shfl_xor(pb, 1);
          if (!(l15 & 1))
            ((unsigned*)route)[(obase + dh) >> 1] = pb | (other << 16);
        } else {
          long col = n0 + wc + j * 16 + l15;
          unsigned bits = __float_as_uint(v);
          unsigned other = __shfl_xor(bits, 1);
          if (!(l15 & 1)) {
            uint2 pr; pr.x = bits; pr.y = other;
            *(uint2*)((float*)Cout + row * N + col) = pr;
          }
        }
      }
    }
  }
}

// ---- vt[bh*128 + d][s] = vb[bh][s][d] (contiguous source, transpose via LDS) ----
__global__ __launch_bounds__(256) void k_extract_vt(const u16* __restrict__ vb,
                                                    u16* __restrict__ vt) {
  __shared__ __attribute__((aligned(16))) u16 Vb[64][136];
  int t = threadIdx.x;
  int s0 = blockIdx.x * 64;
  int bh = blockIdx.y;
  long inbase = ((long)bh * 2048 + s0) * 128;
#pragma unroll
  for (int it = 0; it < 4; ++it) {
    int ci = it * 256 + t;
    int s = ci >> 4, ch = ci & 15;
    int4 v = *(const int4*)(vb + inbase + s * 128 + ch * 8);
    *(int4*)(&Vb[s][ch * 8]) = v;
  }
  __syncthreads();
  long outbase = (long)bh * 128 * 2048 + s0;
#pragma unroll
  for (int it = 0; it < 4; ++it) {
    int ci = it * 256 + t;
    int d = ci >> 3, ch = ci & 7, sb = ch * 8;
    unsigned p0 = Vb[sb + 0][d] | ((unsigned)Vb[sb + 1][d] << 16);
    unsigned p1 = Vb[sb + 2][d] | ((unsigned)Vb[sb + 3][d] << 16);
    unsigned p2 = Vb[sb + 4][d] | ((unsigned)Vb[sb + 5][d] << 16);
    unsigned p3 = Vb[sb + 6][d] | ((unsigned)Vb[sb + 7][d] << 16);
    *(int4*)(vt + outbase + (long)d * 2048 + sb) = make_int4(p0, p1, p2, p3);
  }
}

// ---------------- flash attention v2 (round-4 config): 32x32x16, S^T ----------------
// Block: 4 waves, 128 q-rows (wave w owns 32 q). 64-key tiles, full K loop/wave.
// S^T = K*Q^T; P^T in-register (exp2, no max); O^T = V^T*P^T.
// Q from contiguous qb, K staged from contiguous kb, V^T from vt.
__global__ __launch_bounds__(256, 2) void k_flash(const u16* __restrict__ qb,
                                                  const u16* __restrict__ kb,
                                                  const u16* __restrict__ vt,
                                                  u16* __restrict__ attn) {
  __shared__ __attribute__((aligned(16))) u16 Ks[64 * 128];   // [key][dh], chunk-swizzled
  __shared__ __attribute__((aligned(16))) u16 Vts[128 * 64];  // [dh][key], chunk-swizzled
  int t = threadIdx.x;
  int lane = t & 63, w = t >> 6, l31 = lane & 31, h = lane >> 5;
  int q0 = blockIdx.x * 128 + w * 32;
  int bh = blockIdx.y, b = bh >> 4, hd = bh & 15;

  // Q B-frags from contiguous qb: lane holds Q[q0+l31][dht*16 + h*8 + j]
  const u16* qbase = qb + ((long)bh * 2048 + q0 + l31) * 128;
  U128 qf[8];
#pragma unroll
  for (int dht = 0; dht < 8; ++dht)
    qf[dht].i = *(const int4*)(qbase + dht * 16 + h * 8);

  f32x16 O[4] = {};  // O^T: col=q, rows=dh (4 blocks of 32)
  float lsum = 0.f;
  const float CEXP = 0.08838834764831845f * 1.4426950408889634f;  // cs*log2(e)
  const u16* kbh = kb + (long)bh * 2048 * 128;
  long vbase = (long)bh * 128 * 2048;

  for (int k0 = 0; k0 < 2048; k0 += 64) {
    __syncthreads();
#pragma unroll
    for (int it = 0; it < 4; ++it) {  // K tile: 64 keys x 128 dh (contiguous source)
      int ci = it * 256 + t;
      int key = ci >> 4, cp = ci & 15, cl = cp ^ (key & 7);
      gll16(kbh + (long)(k0 + key) * 128 + cl * 8, Ks + ci * 8);
    }
#pragma unroll
    for (int it = 0; it < 4; ++it) {  // V^T tile: 128 dh x 64 keys
      int ci = it * 256 + t;
      int d = ci >> 3, cp = ci & 7, cl = cp ^ (d & 7);
      gll16(vt + vbase + (long)d * 2048 + k0 + cl * 8, Vts + ci * 8);
    }
    __syncthreads();

    // S^T = K * Q^T  (two 32-key blocks)
    f32x16 St[2] = {};
#pragma unroll
    for (int kb2 = 0; kb2 < 2; ++kb2) {
      int row = kb2 * 32 + l31, sw = row & 7;
      const u16* kr = Ks + row * 128;
#pragma unroll
      for (int dht = 0; dht < 8; ++dht) {
        U128 kf;
        kf.i = *(const int4*)(kr + (((dht * 2 + h) ^ sw) << 3));
        St[kb2] = mfma32(kf, qf[dht], St[kb2]);
      }
    }

    // P = exp(S*cs) without max subtraction; accumulate row-sum (all regs share q)
    float pk[2][16];
#pragma unroll
    for (int kb2 = 0; kb2 < 2; ++kb2)
#pragma unroll
      for (int r = 0; r < 16; ++r) {
        float p = EXP2F(St[kb2][r] * CEXP);
        pk[kb2][r] = p;
        lsum += p;
      }

    // Build P^T B-frags via lane-half exchange
    U128 pf[4];
#pragma unroll
    for (int kb2 = 0; kb2 < 2; ++kb2)
#pragma unroll
      for (int g = 0; g < 2; ++g) {
        float tmp[4], recv[4], lo[4], hi[4];
#pragma unroll
        for (int i = 0; i < 4; ++i)
          tmp[i] = h ? pk[kb2][g * 8 + i] : pk[kb2][g * 8 + 4 + i];
#pragma unroll
        for (int i = 0; i < 4; ++i) recv[i] = __shfl_xor(tmp[i], 32);
#pragma unroll
        for (int i = 0; i < 4; ++i) {
          lo[i] = h ? recv[i] : pk[kb2][g * 8 + i];
          hi[i] = h ? pk[kb2][g * 8 + 4 + i] : recv[i];
        }
        unsigned w0 = f2b(lo[0]) | ((unsigned)f2b(lo[1]) << 16);
        unsigned w1 = f2b(lo[2]) | ((unsigned)f2b(lo[3]) << 16);
        unsigned w2 = f2b(hi[0]) | ((unsigned)f2b(hi[1]) << 16);
        unsigned w3 = f2b(hi[2]) | ((unsigned)f2b(hi[3]) << 16);
        pf[kb2 * 2 + g].i = make_int4(w0, w1, w2, w3);
      }

    // O^T += V^T * P^T
#pragma unroll
    for (int kt = 0; kt < 4; ++kt)
#pragma unroll
      for (int dht = 0; dht < 4; ++dht) {
        int vrow = dht * 32 + l31, vsw = vrow & 7;
        U128 vf;
        vf.i = *(const int4*)(Vts + vrow * 64 + (((kt * 2 + h) ^ vsw) << 3));
        O[dht] = mfma32(vf, pf[kt], O[dht]);
      }
  }

  // finalize: l[q] = own + partner half; divide; packed dwordx2 stores
  float ltot = lsum + __shfl_xor(lsum, 32);
  float inv = 1.f / ltot;
  long orow = (long)b * 2048 + q0 + l31;
  u16* ob = attn + orow * 2048 + hd * 128;
#pragma unroll
  for (int dht = 0; dht < 4; ++dht)
#pragma unroll
    for (int g = 0; g < 4; ++g) {
      int dh = dht * 32 + g * 8 + h * 4;  // rows (reg&3)+8*(reg>>2)+4h, regs 4g..4g+3
      float v0 = O[dht][4 * g + 0] * inv, v1 = O[dht][4 * g + 1] * inv;
      float v2 = O[dht][4 * g + 2] * inv, v3 = O[dht][4 * g + 3] * inv;
      uint2 pkd;
      pkd.x = f2b(v0) | ((unsigned)f2b(v1) << 16);
      pkd.y = f2b(v2) | ((unsigned)f2b(v3) << 16);
      *(uint2*)(ob + dh) = pkd;
    }
}

extern "C" void kernel_launch(void* const* d_in, const int* in_sizes, int n_in,
                              void* d_out, int out_size, void* d_ws, size_t ws_size,
                              hipStream_t stream) {
  const float* x    = (const float*)d_in[0];
  const float* Wqkv = (const float*)d_in[1];
  const float* bqkv = (const float*)d_in[2];
  const float* Wout = (const float*)d_in[3];
  const float* bout = (const float*)d_in[4];
  float* out = (float*)d_out;
  char* ws = (char*)d_ws;

  // Workspace overlay (peak 75,497,472 B in ws; d_out = 33.55 MB doubles as scratch):
  //   phase A: xb (bf16 x, 16.78 MB)  -> d_out[0, 16.78M)  [dead after GEMM1]
  //            wqkvt (25.17 MB)       -> ws[0, 25165824)   [dead after GEMM1]
  //            qb  [bh][s][dh]        -> ws[25165824, 41943040)
  //            kb  [bh][s][dh]        -> ws[41943040, 58720256)
  //            vb  [bh][s][dh]        -> ws[58720256, 75497472)  [dead after extract]
  //   phase B: vt (16.78 MB)          -> d_out[0, 16.78M)       [xb dead]
  //            woutt (8.39 MB)        -> ws[0, 8388608)
  //            attnb (16.78 MB)       -> ws[8388608, 25165824)
  //   qb/kb/vt dead before GEMM2 writes d_out.
  if (ws_size < 75497472u) return;  // diagnostic guard: fail cleanly, not fault

  u16* xb    = (u16*)d_out;
  u16* wqkvt = (u16*)(ws);
  u16* qbuf  = (u16*)(ws + 25165824);
  u16* kbuf  = (u16*)(ws + 41943040);
  u16* vbuf  = (u16*)(ws + 58720256);
  u16* vtb   = (u16*)d_out;            // after GEMM1 (xb dead)
  u16* woutt = (u16*)(ws);             // after GEMM1 (wqkvt dead)
  u16* attnb = (u16*)(ws + 8388608);   // after GEMM1

  // x: 2*2048*2048 = 8,388,608 floats = 2,097,152 float4s
  k_conv_bf16<<<8192, 256, 0, stream>>>(x, xb, 2097152);
  k_transpose_f2b<<<dim3(96, 32), 256, 0, stream>>>(Wqkv, wqkvt, 2048, 6144);
  k_gemm_bt<1><<<dim3(48, 32), 256, 0, stream>>>(xb, wqkvt, bqkv, nullptr,
                                                 qbuf, kbuf, vbuf, 4096, 6144, 2048);
  k_extract_vt<<<dim3(32, 32), 256, 0, stream>>>(vbuf, vtb);
  k_transpose_f2b<<<dim3(32, 32), 256, 0, stream>>>(Wout, woutt, 2048, 2048);
  k_flash<<<dim3(16, 32), 256, 0, stream>>>(qbuf, kbuf, vtb, attnb);
  k_gemm_bt<0><<<dim3(16, 32), 256, 0, stream>>>(attnb, woutt, bout, out,
                                                 nullptr, nullptr, nullptr, 4096, 2048, 2048);
}